// Round 11
// baseline (61.883 us; speedup 1.0000x reference)
//
#include <hip/hip_runtime.h>

typedef _Float16 half8 __attribute__((ext_vector_type(8)));
typedef _Float16 half2v __attribute__((ext_vector_type(2)));
typedef float f32x4 __attribute__((ext_vector_type(4)));

#define P_DIM 1024
#define BM 64
#define NH 8          // half-stages of K=128 floats each
#define AH_ROW 136    // f16/row: 128 data + 8 pad -> 272 B stride (16B-aligned rows)

// FRAGMENT-MAJOR weights (proven R6/R10): B-frag load = 64 lanes x 16 B = 1 KB.
// Wf2[((S*4 + t)*64 + l)*8 + j] = W[t*16 + (l&15)][S*32 + (l>>4)*8 + j]
// rows 0-47 = W_w, 48-55 = G_w, 56-63 = 0.  S = k-step 0..31, t = n-tile 0..3.
__global__ __launch_bounds__(256) void prep_weights(
    const float* __restrict__ Gw, const float* __restrict__ Gb,
    const float* __restrict__ Ww, const float* __restrict__ Wb,
    _Float16* __restrict__ Wf2, float* __restrict__ biasC) {
  int i = blockIdx.x * 256 + threadIdx.x;   // 0 .. 65535
  int j = i & 7;
  int l = (i >> 3) & 63;
  int t = (i >> 9) & 3;
  int S = i >> 11;
  int row = t * 16 + (l & 15);
  int k   = S * 32 + (l >> 4) * 8 + j;
  float v = 0.0f;
  if (row < 48) v = Ww[row * P_DIM + k];
  else if (row < 56) v = Gw[(row - 48) * P_DIM + k];
  Wf2[i] = (_Float16)v;
  if (i < 64) {
    float bv = 0.0f;
    if (i < 48) bv = Wb[i];
    else if (i < 56) bv = Gb[i - 48];
    biasC[i] = bv;
  }
}

// 64x16 wave tile: wave w owns n-tile w only. Per chunk c: 2 B-frags
// (S = 2c, 2c+1) at bytes (S*4 + w)*1024; bgw includes +w*1024.
#define LOAD_B(dst, c) do { const char* p_ = bgw + (size_t)(c) * 8192; \
    dst[0] = *(const half8*)(p_);          dst[1] = *(const half8*)(p_ + 4096); \
  } while (0)

// Per chunk cc (parity within half-stage): 4 m-tiles x 2 S-steps, A straight
// from f16 LDS (no read-side cvt), 8 ds_read_b128 + 8 MFMA.
#define BODY(bX, cc) do { \
    _Pragma("unroll") \
    for (int m_ = 0; m_ < 4; ++m_) { \
      half8 a0_ = *(const half8*)&Ah[m_ * 16 + l15][(cc) * 64 + q8]; \
      half8 a1_ = *(const half8*)&Ah[m_ * 16 + l15][(cc) * 64 + 32 + q8]; \
      acc[m_] = __builtin_amdgcn_mfma_f32_16x16x32_f16(a0_, bX[0], acc[m_], 0, 0, 0); \
      acc[m_] = __builtin_amdgcn_mfma_f32_16x16x32_f16(a1_, bX[1], acc[m_], 0, 0, 0); \
    } \
  } while (0)

__global__ __launch_bounds__(256, 3) void fused_gate(
    const float* __restrict__ x, const _Float16* __restrict__ Wf2,
    const float* __restrict__ biasC, float* __restrict__ out) {
  // f16 A-stage during the loop (typed, R1-proven store pattern);
  // epilogue scratch S aliases it afterwards. 64*136*2 = 17408 B.
  __shared__ __align__(16) _Float16 Ah[BM][AH_ROW];

  const int tid  = threadIdx.x;
  const int lane = tid & 63;
  const int w    = tid >> 6;        // wave id 0..3 -> n-tile w
  const int row0 = blockIdx.x * BM;
  const int l15  = lane & 15;
  const int q    = lane >> 4;
  const int q8   = q * 8;           // k-octet element offset

  // A staging (R6 pattern): wave w stages rows w*16..w*16+15;
  // per (row, half-stage) one dwordx2 per lane = 512 B contiguous burst.
  const char* xg = (const char*)(x + (size_t)(row0 + w * 16) * P_DIM) + lane * 8;
  // B fragment-major, this wave's single n-tile (t = w)
  const char* bgw = (const char*)Wf2 + lane * 16 + (size_t)w * 1024;

  f32x4 acc[4];
#pragma unroll
  for (int t = 0; t < 4; ++t) acc[t] = (f32x4){0.f, 0.f, 0.f, 0.f};

  float2 pf[16];
#pragma unroll
  for (int i = 0; i < 16; ++i) pf[i] = *(const float2*)(xg + i * 4096);  // half-stage 0

  half8 bA[2], bB[2];
  LOAD_B(bA, 0);

  for (int h = 0; h < NH; ++h) {
    if (h) __syncthreads();          // previous half-stage fully consumed
    // cvt f32->f16 at stage time; lane l writes elements [2l, 2l+2) of each row
    // (fully typed stores, same element type as the read side)
#pragma unroll
    for (int i = 0; i < 16; ++i) {
      half2v hv;
      hv[0] = (_Float16)pf[i].x;
      hv[1] = (_Float16)pf[i].y;
      *(half2v*)&Ah[w * 16 + i][2 * lane] = hv;
    }
    __syncthreads();                 // stage visible to all waves (cross-wave reads)
    const int c0 = h * 2;
    // B for chunk c0+1 FIRST (older in VMEM FIFO than the HBM prefetch below,
    // so BODY(bB)'s wait does NOT drain the prefetch)
    LOAD_B(bB, c0 + 1);
    // next half-stage A prefetch (HBM, youngest; drained at next stage top)
    if (h + 1 < NH) {
#pragma unroll
      for (int i = 0; i < 16; ++i)
        pf[i] = *(const float2*)(xg + i * 4096 + (h + 1) * 512);
    }
    BODY(bA, 0);                     // chunk c0 (bA pre-loaded)
    BODY(bB, 1);                     // chunk c0+1
    if (h + 1 < NH)
      LOAD_B(bA, c0 + 2);            // next even chunk; drains at next stage top
  }

  __syncthreads();                   // Ah (A-stage) dead from here on
  float (*S)[65] = (float (*)[65])&Ah[0][0];   // epilogue scratch aliases Ah (16640 <= 17408 B)

  // acc -> S with bias. Wave w: cols w*16 + l15, rows m*16 + q*4 + rr.
  // D layout: col = lane&15, row = (lane>>4)*4 + reg.
  {
    const int col = w * 16 + l15;
    const float bias = biasC[col];
#pragma unroll
    for (int m = 0; m < 4; ++m) {
#pragma unroll
      for (int rr = 0; rr < 4; ++rr) {
        S[m * 16 + q * 4 + rr][col] = acc[m][rr] + bias;
      }
    }
  }
  __syncthreads();

  // Epilogue: 4 threads/row, experts [sub*16, sub*16+16)
  const int r2  = tid >> 2;
  const int sub = tid & 3;

  float lg[8];
#pragma unroll
  for (int k = 0; k < 8; ++k) lg[k] = S[r2][48 + k];
  float mx = lg[0];
#pragma unroll
  for (int k = 1; k < 8; ++k) mx = fmaxf(mx, lg[k]);
  float wk[8];
  float ssum = 0.f;
#pragma unroll
  for (int k = 0; k < 8; ++k) { wk[k] = expf(lg[k] - mx); ssum += wk[k]; }
  const float inv = 1.0f / ssum;

  float mix[16];
#pragma unroll
  for (int i = 0; i < 16; ++i) mix[i] = 0.f;

#pragma unroll
  for (int k = 0; k < 8; ++k) {
    float z[6];
#pragma unroll
    for (int j = 0; j < 6; ++j) {
      float tt = S[r2][k * 6 + j];
      float tc = fminf(fmaxf(tt, -0.25f), 0.25f);
      // smooth_step: -16 tc^3 + 3 tc + 0.5
      z[j] = fmaf(tc, fmaf(-16.0f * tc, tc, 3.0f), 0.5f);
    }
    float f4v = (sub & 1) ? z[4] : 1.0f - z[4];
    float f5v = (sub & 2) ? z[5] : 1.0f - z[5];
    float wf = wk[k] * inv * f4v * f5v;
    float t2[2], t4[4], t8[8], t16[16];
    t2[0] = 1.0f - z[0]; t2[1] = z[0];
#pragma unroll
    for (int i = 0; i < 2; ++i) { t4[i] = t2[i] * (1.0f - z[1]); t4[i + 2] = t2[i] * z[1]; }
#pragma unroll
    for (int i = 0; i < 4; ++i) { t8[i] = t4[i] * (1.0f - z[2]); t8[i + 4] = t4[i] * z[2]; }
#pragma unroll
    for (int i = 0; i < 8; ++i) { t16[i] = t8[i] * (1.0f - z[3]); t16[i + 8] = t8[i] * z[3]; }
#pragma unroll
    for (int i = 0; i < 16; ++i) mix[i] = fmaf(wf, t16[i], mix[i]);
  }

  float* op = out + (size_t)(row0 + r2) * 64 + sub * 16;
#pragma unroll
  for (int g = 0; g < 4; ++g) {
    float4 o;
    o.x = mix[4 * g + 0]; o.y = mix[4 * g + 1];
    o.z = mix[4 * g + 2]; o.w = mix[4 * g + 3];
    ((float4*)op)[g] = o;
  }
}

extern "C" void kernel_launch(void* const* d_in, const int* in_sizes, int n_in,
                              void* d_out, int out_size, void* d_ws, size_t ws_size,
                              hipStream_t stream) {
  const float* x  = (const float*)d_in[0];
  const float* Gw = (const float*)d_in[1];
  const float* Gb = (const float*)d_in[2];
  const float* Ww = (const float*)d_in[3];
  const float* Wb = (const float*)d_in[4];
  float* out = (float*)d_out;

  _Float16* Wf2  = (_Float16*)d_ws;
  float*    bias = (float*)((char*)d_ws + 64 * P_DIM * sizeof(_Float16));

  const int B = in_sizes[0] / P_DIM;

  prep_weights<<<dim3(256), dim3(256), 0, stream>>>(Gw, Gb, Ww, Wb, Wf2, bias);
  fused_gate<<<dim3(B / BM), dim3(256), 0, stream>>>(x, Wf2, bias, out);
  (void)n_in; (void)out_size; (void)ws_size;
}

// Round 12
// 57.547 us; speedup vs baseline: 1.0754x; 1.0754x over previous
//
#include <hip/hip_runtime.h>

typedef _Float16 half8 __attribute__((ext_vector_type(8)));
typedef float f32x4 __attribute__((ext_vector_type(4)));
typedef float f4 __attribute__((ext_vector_type(4)));

#define P_DIM 1024
#define BM 64
#define NH 8          // half-stages of K=128 floats each
#define AF_ROW 132    // LDS A row: 128 floats + 4 pad = 528 B stride (R10-proven)

// FRAGMENT-MAJOR weights (proven R6/R10): B-frag = 64 lanes x 16 B = 1 KB.
// Wf2[((S*4 + t)*64 + l)*8 + j] = W[t*16 + (l&15)][S*32 + (l>>4)*8 + j]
// rows 0-47 = W_w, 48-55 = G_w, 56-63 = 0.  S = k-step 0..31, t = n-tile 0..3.
__global__ __launch_bounds__(256) void prep_weights(
    const float* __restrict__ Gw, const float* __restrict__ Gb,
    const float* __restrict__ Ww, const float* __restrict__ Wb,
    _Float16* __restrict__ Wf2, float* __restrict__ biasC) {
  int i = blockIdx.x * 256 + threadIdx.x;   // 0 .. 65535
  int j = i & 7;
  int l = (i >> 3) & 63;
  int t = (i >> 9) & 3;
  int S = i >> 11;
  int row = t * 16 + (l & 15);
  int k   = S * 32 + (l >> 4) * 8 + j;
  float v = 0.0f;
  if (row < 48) v = Ww[row * P_DIM + k];
  else if (row < 56) v = Gw[(row - 48) * P_DIM + k];
  Wf2[i] = (_Float16)v;
  if (i < 64) {
    float bv = 0.0f;
    if (i < 48) bv = Wb[i];
    else if (i < 56) bv = Gb[i - 48];
    biasC[i] = bv;
  }
}

// BODY chunk cc (0/1 within half-stage): B frags from LDS (frag(s,t) of chunk
// cc at LDS byte ((2cc+s)*4+t)*1024 + lane*16; BsR folds in lane*16 + tb*1024),
// A from f32 LDS stage + cvt (R10-verbatim), 8 MFMA with R10's proven pairing.
#define BODY(cc) do { \
    half8 b0_ = *(const half8*)(BsR + (size_t)((2*(cc)  )*4    ) * 1024); \
    half8 b1_ = *(const half8*)(BsR + (size_t)((2*(cc)+1)*4    ) * 1024); \
    half8 b2_ = *(const half8*)(BsR + (size_t)((2*(cc)  )*4 + 1) * 1024); \
    half8 b3_ = *(const half8*)(BsR + (size_t)((2*(cc)+1)*4 + 1) * 1024); \
    f4 a0_[4], a1_[4]; \
    { const char* p0 = Abase0 + (cc) * 256; \
      a0_[0] = *(const f4*)(p0);       a0_[1] = *(const f4*)(p0 + 16); \
      a0_[2] = *(const f4*)(p0 + 128); a0_[3] = *(const f4*)(p0 + 144); \
      const char* p1 = Abase1 + (cc) * 256; \
      a1_[0] = *(const f4*)(p1);       a1_[1] = *(const f4*)(p1 + 16); \
      a1_[2] = *(const f4*)(p1 + 128); a1_[3] = *(const f4*)(p1 + 144); } \
    half8 h00_, h01_, h10_, h11_; \
    h00_[0]=(_Float16)a0_[0][0]; h00_[1]=(_Float16)a0_[0][1]; h00_[2]=(_Float16)a0_[0][2]; h00_[3]=(_Float16)a0_[0][3]; \
    h00_[4]=(_Float16)a0_[1][0]; h00_[5]=(_Float16)a0_[1][1]; h00_[6]=(_Float16)a0_[1][2]; h00_[7]=(_Float16)a0_[1][3]; \
    h01_[0]=(_Float16)a0_[2][0]; h01_[1]=(_Float16)a0_[2][1]; h01_[2]=(_Float16)a0_[2][2]; h01_[3]=(_Float16)a0_[2][3]; \
    h01_[4]=(_Float16)a0_[3][0]; h01_[5]=(_Float16)a0_[3][1]; h01_[6]=(_Float16)a0_[3][2]; h01_[7]=(_Float16)a0_[3][3]; \
    h10_[0]=(_Float16)a1_[0][0]; h10_[1]=(_Float16)a1_[0][1]; h10_[2]=(_Float16)a1_[0][2]; h10_[3]=(_Float16)a1_[0][3]; \
    h10_[4]=(_Float16)a1_[1][0]; h10_[5]=(_Float16)a1_[1][1]; h10_[6]=(_Float16)a1_[1][2]; h10_[7]=(_Float16)a1_[1][3]; \
    h11_[0]=(_Float16)a1_[2][0]; h11_[1]=(_Float16)a1_[2][1]; h11_[2]=(_Float16)a1_[2][2]; h11_[3]=(_Float16)a1_[2][3]; \
    h11_[4]=(_Float16)a1_[3][0]; h11_[5]=(_Float16)a1_[3][1]; h11_[6]=(_Float16)a1_[3][2]; h11_[7]=(_Float16)a1_[3][3]; \
    acc[0] = __builtin_amdgcn_mfma_f32_16x16x32_f16(h00_, b0_, acc[0], 0, 0, 0); \
    acc[0] = __builtin_amdgcn_mfma_f32_16x16x32_f16(h01_, b1_, acc[0], 0, 0, 0); \
    acc[1] = __builtin_amdgcn_mfma_f32_16x16x32_f16(h00_, b2_, acc[1], 0, 0, 0); \
    acc[1] = __builtin_amdgcn_mfma_f32_16x16x32_f16(h01_, b3_, acc[1], 0, 0, 0); \
    acc[2] = __builtin_amdgcn_mfma_f32_16x16x32_f16(h10_, b0_, acc[2], 0, 0, 0); \
    acc[2] = __builtin_amdgcn_mfma_f32_16x16x32_f16(h11_, b1_, acc[2], 0, 0, 0); \
    acc[3] = __builtin_amdgcn_mfma_f32_16x16x32_f16(h10_, b2_, acc[3], 0, 0, 0); \
    acc[3] = __builtin_amdgcn_mfma_f32_16x16x32_f16(h11_, b3_, acc[3], 0, 0, 0); \
  } while (0)

__global__ __launch_bounds__(256, 3) void fused_gate(
    const float* __restrict__ x, const _Float16* __restrict__ Wf2,
    const float* __restrict__ biasC, float* __restrict__ out) {
  // A-stage (f32, R10-proven); epilogue scratch S aliases it afterwards.
  __shared__ __align__(16) float Af[BM][AF_ROW];   // 33792 B
  // B-stage: one half-stage's 16 frags (16 KB), single-buffered — the
  // stage-top barrier orders overwrite vs. previous half-stage's reads.
  __shared__ __align__(16) _Float16 BsH[8192];     // 16384 B  (total 50176)

  const int tid  = threadIdx.x;
  const int lane = tid & 63;
  const int w    = tid >> 6;        // wave id 0..3
  const int row0 = blockIdx.x * BM;
  const int l15  = lane & 15;
  const int q    = lane >> 4;

  // Wave tile (R10): rows [mrow, mrow+32), cols [ncol, ncol+32)
  const int mrow = (w >> 1) * 32;
  const int ncol = (w & 1) * 32;
  const int tb   = (w & 1) * 2;     // first n-tile of this wave's column pair

  // A staging: wave w stages rows w*16..w*16+15; per (row, half-stage) one
  // dwordx2 per lane = 512 B contiguous burst.
  const char* xg = (const char*)(x + (size_t)(row0 + w * 16) * P_DIM) + lane * 8;
  // B global: wave w loads frag-slots w*4..w*4+3 of each half-stage's 16 KB
  const char* bgG = (const char*)Wf2 + (size_t)(w * 4) * 1024 + lane * 16;

  char* Aw = (char*)&Af[w * 16][0] + lane * 8;                 // + i*528 per row
  const char* Abase0 = (const char*)&Af[mrow + l15][0] + q * 32;
  const char* Abase1 = Abase0 + 16 * 528;
  char* BsW = (char*)BsH + (size_t)(w * 4) * 1024 + lane * 16; // + i*1024
  const char* BsR = (const char*)BsH + (size_t)tb * 1024 + lane * 16;

  f32x4 acc[4];
#pragma unroll
  for (int t = 0; t < 4; ++t) acc[t] = (f32x4){0.f, 0.f, 0.f, 0.f};

  // prologue: A + B register-prefetch for half-stage 0
  float2 pf[16];
#pragma unroll
  for (int i = 0; i < 16; ++i) pf[i] = *(const float2*)(xg + i * 4096);
  half8 bR[4];
#pragma unroll
  for (int i = 0; i < 4; ++i) bR[i] = *(const half8*)(bgG + (size_t)i * 1024);

  for (int h = 0; h < NH; ++h) {
    if (h) __syncthreads();          // prev half-stage fully consumed (A and B)
    // stage A (f32, R10 pattern) and B (half8 both sides) into LDS
#pragma unroll
    for (int i = 0; i < 16; ++i)
      *(float2*)(Aw + i * 528) = pf[i];
#pragma unroll
    for (int i = 0; i < 4; ++i)
      *(half8*)(BsW + (size_t)i * 1024) = bR[i];
    __syncthreads();                 // stage visible to all waves
    // issue next half-stage's loads (drained at next stage-top barrier)
    if (h + 1 < NH) {
      const size_t boff = (size_t)(h + 1) * 16384;
#pragma unroll
      for (int i = 0; i < 4; ++i)
        bR[i] = *(const half8*)(bgG + boff + (size_t)i * 1024);
#pragma unroll
      for (int i = 0; i < 16; ++i)
        pf[i] = *(const float2*)(xg + i * 4096 + (h + 1) * 512);
    }
    BODY(0);                         // chunk 2h   (A, B from LDS; no global waits)
    BODY(1);                         // chunk 2h+1
  }

  __syncthreads();                   // Af dead from here on
  float (*S)[65] = (float (*)[65])&Af[0][0];   // epilogue scratch aliases Af

  // acc -> S with bias (R10-verbatim). Tile (m,j): rows mrow+m*16+q*4+rr,
  // cols ncol+j*16+l15. D layout: col = lane&15, row = (lane>>4)*4 + reg.
#pragma unroll
  for (int m = 0; m < 2; ++m) {
#pragma unroll
    for (int j = 0; j < 2; ++j) {
      const int col = ncol + j * 16 + l15;
      float bias = biasC[col];
#pragma unroll
      for (int rr = 0; rr < 4; ++rr) {
        S[mrow + m * 16 + q * 4 + rr][col] = acc[m * 2 + j][rr] + bias;
      }
    }
  }
  __syncthreads();

  // Epilogue: 4 threads/row, experts [sub*16, sub*16+16)
  const int r2  = tid >> 2;
  const int sub = tid & 3;

  float lg[8];
#pragma unroll
  for (int k = 0; k < 8; ++k) lg[k] = S[r2][48 + k];
  float mx = lg[0];
#pragma unroll
  for (int k = 1; k < 8; ++k) mx = fmaxf(mx, lg[k]);
  float wk[8];
  float ssum = 0.f;
#pragma unroll
  for (int k = 0; k < 8; ++k) { wk[k] = expf(lg[k] - mx); ssum += wk[k]; }
  const float inv = 1.0f / ssum;

  float mix[16];
#pragma unroll
  for (int i = 0; i < 16; ++i) mix[i] = 0.f;

#pragma unroll
  for (int k = 0; k < 8; ++k) {
    float z[6];
#pragma unroll
    for (int j = 0; j < 6; ++j) {
      float tt = S[r2][k * 6 + j];
      float tc = fminf(fmaxf(tt, -0.25f), 0.25f);
      // smooth_step: -16 tc^3 + 3 tc + 0.5
      z[j] = fmaf(tc, fmaf(-16.0f * tc, tc, 3.0f), 0.5f);
    }
    float f4v = (sub & 1) ? z[4] : 1.0f - z[4];
    float f5v = (sub & 2) ? z[5] : 1.0f - z[5];
    float wf = wk[k] * inv * f4v * f5v;
    float t2[2], t4[4], t8[8], t16[16];
    t2[0] = 1.0f - z[0]; t2[1] = z[0];
#pragma unroll
    for (int i = 0; i < 2; ++i) { t4[i] = t2[i] * (1.0f - z[1]); t4[i + 2] = t2[i] * z[1]; }
#pragma unroll
    for (int i = 0; i < 4; ++i) { t8[i] = t4[i] * (1.0f - z[2]); t8[i + 4] = t4[i] * z[2]; }
#pragma unroll
    for (int i = 0; i < 8; ++i) { t16[i] = t8[i] * (1.0f - z[3]); t16[i + 8] = t8[i] * z[3]; }
#pragma unroll
    for (int i = 0; i < 16; ++i) mix[i] = fmaf(wf, t16[i], mix[i]);
  }

  float* op = out + (size_t)(row0 + r2) * 64 + sub * 16;
#pragma unroll
  for (int g = 0; g < 4; ++g) {
    float4 o;
    o.x = mix[4 * g + 0]; o.y = mix[4 * g + 1];
    o.z = mix[4 * g + 2]; o.w = mix[4 * g + 3];
    ((float4*)op)[g] = o;
  }
}

extern "C" void kernel_launch(void* const* d_in, const int* in_sizes, int n_in,
                              void* d_out, int out_size, void* d_ws, size_t ws_size,
                              hipStream_t stream) {
  const float* x  = (const float*)d_in[0];
  const float* Gw = (const float*)d_in[1];
  const float* Gb = (const float*)d_in[2];
  const float* Ww = (const float*)d_in[3];
  const float* Wb = (const float*)d_in[4];
  float* out = (float*)d_out;

  _Float16* Wf2  = (_Float16*)d_ws;
  float*    bias = (float*)((char*)d_ws + 64 * P_DIM * sizeof(_Float16));

  const int B = in_sizes[0] / P_DIM;

  prep_weights<<<dim3(256), dim3(256), 0, stream>>>(Gw, Gb, Ww, Wb, Wf2, bias);
  fused_gate<<<dim3(B / BM), dim3(256), 0, stream>>>(x, Wf2, bias, out);
  (void)n_in; (void)out_size; (void)ws_size;
}